// Round 14
// baseline (61.840 us; speedup 1.0000x reference)
//
#include <hip/hip_runtime.h>

#define B_ 32
#define P_ 4096
#define Q_ 64
#define D_ 128

#define PART_STRIDE 772         // [L, S, v:128, mxH:128, mnH:128, mxC:128, mxHC:128, mxM:128]
#define NCHUNK 16
#define CHUNK_ROWS 256
// workspace: Thi[32][16KB] | Tlo[32][16KB] | Ut[32][16KB] | part[512][772] floats
#define TWS_BYTES (96*16384)

typedef __attribute__((ext_vector_type(8))) short bf16x8;
typedef __attribute__((ext_vector_type(4))) float f32x4;

__device__ __forceinline__ unsigned int asu(float x) { return __float_as_uint(x); }
__device__ __forceinline__ float asf(unsigned int x) { return __uint_as_float(x); }

// split-bf16 repack: fa/fb (8 consecutive fp32) -> hi/lo bf16x8 fragments
__device__ __forceinline__ void repack8(const f32x4 fa, const f32x4 fb,
                                        bf16x8* hi, bf16x8* lo) {
  union { bf16x8 v; unsigned int u[4]; } Hh, Ll;
  unsigned int a0 = asu(fa[0]), a1 = asu(fa[1]), a2 = asu(fa[2]), a3 = asu(fa[3]);
  unsigned int c0 = asu(fb[0]), c1 = asu(fb[1]), c2 = asu(fb[2]), c3 = asu(fb[3]);
  Hh.u[0] = (a1 & 0xFFFF0000u) | (a0 >> 16);
  Hh.u[1] = (a3 & 0xFFFF0000u) | (a2 >> 16);
  Hh.u[2] = (c1 & 0xFFFF0000u) | (c0 >> 16);
  Hh.u[3] = (c3 & 0xFFFF0000u) | (c2 >> 16);
  float p0 = fa[0] - asf(a0 & 0xFFFF0000u);
  float p1 = fa[1] - asf(a1 & 0xFFFF0000u);
  float p2 = fa[2] - asf(a2 & 0xFFFF0000u);
  float p3 = fa[3] - asf(a3 & 0xFFFF0000u);
  float p4 = fb[0] - asf(c0 & 0xFFFF0000u);
  float p5 = fb[1] - asf(c1 & 0xFFFF0000u);
  float p6 = fb[2] - asf(c2 & 0xFFFF0000u);
  float p7 = fb[3] - asf(c3 & 0xFFFF0000u);
  Ll.u[0] = (asu(p1) & 0xFFFF0000u) | (asu(p0) >> 16);
  Ll.u[1] = (asu(p3) & 0xFFFF0000u) | (asu(p2) >> 16);
  Ll.u[2] = (asu(p5) & 0xFFFF0000u) | (asu(p4) >> 16);
  Ll.u[3] = (asu(p7) & 0xFFFF0000u) | (asu(p6) >> 16);
  *hi = Hh.v; *lo = Ll.v;
}

// ---------------------------------------------------------------------------
// k_T: T[b,q,d] = sum_e W[d,e]*U[b,q,e]; writes PRE-SWIZZLED bf16 images:
//   Thi/Tlo: bf16 hi/lo of T,  byte (q*256+2d) ^ ((q&7)<<4)   per batch 16 KB
//   Ut:      bf16 of RAW U^T,  byte (d*128+2q) ^ ((d&7)<<4)   per batch 16 KB
// grid 256 = 32 b * 8 q-chunks, 256 threads
// ---------------------------------------------------------------------------
__global__ __launch_bounds__(256) void k_T(const float* __restrict__ U,
                                           const float* __restrict__ W,
                                           char* __restrict__ Tws) {
  __shared__ float Wl[128*132];
  __shared__ float Ul[8*128];
  const int b = blockIdx.x >> 3, qc = blockIdx.x & 7;
  const int t = threadIdx.x;
#pragma unroll
  for (int k = 0; k < 16; ++k) {
    int i = t*4 + k*1024;
    float4 wv = *(const float4*)(W + i);
    int d = i >> 7, e = i & 127;
    *(float4*)(&Wl[d*132 + e]) = wv;
  }
  {
    int i = t*4;
    int q = i >> 7, e = i & 127;
    *(float4*)(&Ul[q*128 + e]) =
        *(const float4*)(U + ((size_t)(b*Q_ + qc*8 + q))*D_ + e);
  }
  __syncthreads();
  const int d = t & 127, qhalf = t >> 7;
  char* Thi = Tws + b*16384;
  char* Tlo = Tws + 32*16384 + b*16384;
  char* Utl = Tws + 64*16384 + b*16384;
#pragma unroll
  for (int pass = 0; pass < 4; ++pass) {
    const int ql = pass*2 + qhalf;
    const int qg = qc*8 + ql;
    float acc = 0.f;
#pragma unroll
    for (int e = 0; e < 128; e += 4) {
      float4 wv = *(float4*)(&Wl[d*132 + e]);
      float4 uv = *(float4*)(&Ul[ql*128 + e]);
      acc += wv.x*uv.x + wv.y*uv.y + wv.z*uv.z + wv.w*uv.w;
    }
    unsigned int au = asu(acc);
    unsigned short hs = (unsigned short)(au >> 16);
    float lo = acc - asf(au & 0xFFFF0000u);
    unsigned short ls = (unsigned short)(asu(lo) >> 16);
    int ta = (qg*256 + 2*d) ^ ((qg & 7) << 4);
    *(unsigned short*)(Thi + ta) = hs;
    *(unsigned short*)(Tlo + ta) = ls;
    // Ut stores RAW U (bf16), NOT T — it is the B operand of c2q = P*U.
    float uval = Ul[ql*128 + d];
    int ua = (d*128 + 2*qg) ^ ((d & 7) << 4);
    *(unsigned short*)(Utl + ua) = (unsigned short)(asu(uval) >> 16);
  }
}

// ---------------------------------------------------------------------------
// k_main v11 (double-pipeline): grid 512 = 32 b * 16 chunks of 256 rows,
// 512 threads (8 waves), exactly 2 blocks/CU (no tail).
// Each wave runs TWO independent chains (half-chunks A=rows 0-127, B=128-255):
//  phase 1: S for one A-tile and one B-tile, shared T fragments, 2 sacc chains
//  phase 2: swapped-operand PV + pools for both halves per iteration
// LDS: T hi+lo 32K | PA 16K | PB 16K | stats 5K = 69 KB.
// ---------------------------------------------------------------------------
__global__ __launch_bounds__(512, 2) void k_main(
    const float* __restrict__ H, const float* __restrict__ M,
    const int* __restrict__ tok, const char* __restrict__ Tws,
    float* __restrict__ part) {
  __shared__ __align__(16) char Tl[32768];  // Thi | Tlo images (swizzled layout)
  __shared__ __align__(16) char PA[16384];  // bf16 [128 p][64 q] swizzled (rows 0-127)
  __shared__ __align__(16) char PB[16384];  // bf16 [128 p][64 q] swizzled (rows 128-255)
  __shared__ __align__(16) float mrow[256];
  __shared__ __align__(16) float rzrow[256];
  __shared__ __align__(16) float prow[256];
  __shared__ __align__(16) float bm[256];   // tk ? 0 : -1e38
  __shared__ int tkl[256];

  const int bid = blockIdx.x;
  const int b = bid >> 4, chunk = bid & 15;
  const int t = threadIdx.x, wv = t >> 6, l = t & 63;
  const int r15 = l & 15, g4 = l >> 4;
  const char* Thi_g = Tws + b*16384;
  const char* Tlo_g = Tws + 32*16384 + b*16384;
  const char* Utl   = Tws + 64*16384 + b*16384;

  // hoisted Ut A-fragments for phase 2 (d-row = wv*16 + r15, k = g4*8 + 32*ks2)
  const int dA = wv*16 + r15;
  bf16x8 au0 = *(const bf16x8*)(Utl + ((dA*128 + g4*16 +  0) ^ ((dA & 7) << 4)));
  bf16x8 au1 = *(const bf16x8*)(Utl + ((dA*128 + g4*16 + 64) ^ ((dA & 7) << 4)));

  // linear coalesced copy of Thi/Tlo images into LDS (layout-preserving)
  {
    const uint4* sh = (const uint4*)Thi_g;
    const uint4* sl = (const uint4*)Tlo_g;
    uint4* dh = (uint4*)Tl;
    uint4* dl = (uint4*)(Tl + 16384);
    dh[t]       = sh[t];
    dh[t + 512] = sh[t + 512];
    dl[t]       = sl[t];
    dl[t + 512] = sl[t + 512];
  }
  if (t < 256) tkl[t] = tok[b*P_ + chunk*CHUNK_ROWS + t];
  __syncthreads();

  const int rowB = b*P_ + chunk*CHUNK_ROWS;

  // ========== phase 1: S + softmax for my A-tile and B-tile (2 chains) ======
  {
    const int lrow0 = wv*16;
    const float* ArowA = H + (size_t)(rowB + lrow0 + r15)*D_;
    const float* ArowB = H + (size_t)(rowB + 128 + lrow0 + r15)*D_;
    // batch-issue all 16 global loads
    f32x4 fa0[4], fb0[4], fa1[4], fb1[4];
#pragma unroll
    for (int ks = 0; ks < 4; ++ks) {
      const float* apA = ArowA + ks*32 + g4*8;
      const float* apB = ArowB + ks*32 + g4*8;
      fa0[ks] = *(const f32x4*)(apA);
      fb0[ks] = *(const f32x4*)(apA + 4);
      fa1[ks] = *(const f32x4*)(apB);
      fb1[ks] = *(const f32x4*)(apB + 4);
    }
    bf16x8 AhA[4], AlA[4], AhB[4], AlB[4];
#pragma unroll
    for (int ks = 0; ks < 4; ++ks) {
      repack8(fa0[ks], fb0[ks], &AhA[ks], &AlA[ks]);
      repack8(fa1[ks], fb1[ks], &AhB[ks], &AlB[ks]);
    }
    f32x4 sA[4], sB[4];
#pragma unroll
    for (int qt = 0; qt < 4; ++qt) {
      sA[qt] = (f32x4){0.f, 0.f, 0.f, 0.f};
      sB[qt] = (f32x4){0.f, 0.f, 0.f, 0.f};
    }
#pragma unroll
    for (int ks = 0; ks < 4; ++ks) {
#pragma unroll
      for (int qt = 0; qt < 4; ++qt) {
        int q = qt*16 + r15;
        int off = (q*256 + ks*64 + g4*16) ^ ((q & 7) << 4);
        bf16x8 bh = *(const bf16x8*)(Tl + off);
        bf16x8 bl = *(const bf16x8*)(Tl + 16384 + off);
        sA[qt] = __builtin_amdgcn_mfma_f32_16x16x32_bf16(AlA[ks], bh, sA[qt], 0, 0, 0);
        sA[qt] = __builtin_amdgcn_mfma_f32_16x16x32_bf16(AhA[ks], bl, sA[qt], 0, 0, 0);
        sA[qt] = __builtin_amdgcn_mfma_f32_16x16x32_bf16(AhA[ks], bh, sA[qt], 0, 0, 0);
        sB[qt] = __builtin_amdgcn_mfma_f32_16x16x32_bf16(AlB[ks], bh, sB[qt], 0, 0, 0);
        sB[qt] = __builtin_amdgcn_mfma_f32_16x16x32_bf16(AhB[ks], bl, sB[qt], 0, 0, 0);
        sB[qt] = __builtin_amdgcn_mfma_f32_16x16x32_bf16(AhB[ks], bh, sB[qt], 0, 0, 0);
      }
    }
    // row max over q (two independent shfl chains)
    float mA[4], mB[4];
#pragma unroll
    for (int j = 0; j < 4; ++j) {
      mA[j] = fmaxf(fmaxf(sA[0][j], sA[1][j]), fmaxf(sA[2][j], sA[3][j]));
      mB[j] = fmaxf(fmaxf(sB[0][j], sB[1][j]), fmaxf(sB[2][j], sB[3][j]));
    }
#pragma unroll
    for (int off = 1; off <= 8; off <<= 1)
#pragma unroll
      for (int j = 0; j < 4; ++j) {
        mA[j] = fmaxf(mA[j], __shfl_xor(mA[j], off));
        mB[j] = fmaxf(mB[j], __shfl_xor(mB[j], off));
      }
    // P = exp(S - m) -> bf16 LDS (PA, PB), Z per row
    float ZA[4] = {0.f,0.f,0.f,0.f}, ZB[4] = {0.f,0.f,0.f,0.f};
#pragma unroll
    for (int qt = 0; qt < 4; ++qt)
#pragma unroll
      for (int j = 0; j < 4; ++j) {
        float eA = __expf(sA[qt][j] - mA[j]);
        float eB = __expf(sB[qt][j] - mB[j]);
        ZA[j] += eA;
        ZB[j] += eB;
        int p = lrow0 + g4*4 + j, q = qt*16 + r15;
        int off = (p*128 + 2*q) ^ ((p & 7) << 4);
        *(unsigned short*)(PA + off) = (unsigned short)(asu(eA) >> 16);
        *(unsigned short*)(PB + off) = (unsigned short)(asu(eB) >> 16);
      }
#pragma unroll
    for (int off = 1; off <= 8; off <<= 1)
#pragma unroll
      for (int j = 0; j < 4; ++j) {
        ZA[j] += __shfl_xor(ZA[j], off);
        ZB[j] += __shfl_xor(ZB[j], off);
      }
    if (r15 == 0) {
#pragma unroll
      for (int j = 0; j < 4; ++j) {
        mrow[lrow0 + g4*4 + j]        = mA[j];
        rzrow[lrow0 + g4*4 + j]       = __builtin_amdgcn_rcpf(ZA[j]);
        mrow[128 + lrow0 + g4*4 + j]  = mB[j];
        rzrow[128 + lrow0 + g4*4 + j] = __builtin_amdgcn_rcpf(ZB[j]);
      }
    }
  }
  __syncthreads();

  // block softmax stats over 256 rows (wave-uniform, redundant per wave)
  float q0 = mrow[l], q1 = mrow[l + 64], q2 = mrow[l + 128], q3 = mrow[l + 192];
  float Lm = fmaxf(fmaxf(q0, q1), fmaxf(q2, q3));
#pragma unroll
  for (int off = 1; off <= 32; off <<= 1) Lm = fmaxf(Lm, __shfl_xor(Lm, off));
  float ssum = __expf(q0 - Lm) + __expf(q1 - Lm) + __expf(q2 - Lm) + __expf(q3 - Lm);
#pragma unroll
  for (int off = 1; off <= 32; off <<= 1) ssum += __shfl_xor(ssum, off);
  if (t < 256) {
    prow[t] = __expf(mrow[t] - Lm);
    bm[t]   = tkl[t] ? 0.f : -1.0e38f;
  }
  __syncthreads();

  // ====== phase 2 (swapped, both halves): C[d][p] = mfma(Ut, P^T) ===========
  f32x4 v4  = (f32x4){0.f, 0.f, 0.f, 0.f};
  f32x4 xH4 = (f32x4){-3.0e38f, -3.0e38f, -3.0e38f, -3.0e38f};
  f32x4 nH4 = (f32x4){ 3.0e38f,  3.0e38f,  3.0e38f,  3.0e38f};
  f32x4 xC4 = (f32x4){-3.0e38f, -3.0e38f, -3.0e38f, -3.0e38f};
  f32x4 xHC4= (f32x4){-3.0e38f, -3.0e38f, -3.0e38f, -3.0e38f};
  f32x4 xM4 = (f32x4){-3.0e38f, -3.0e38f, -3.0e38f, -3.0e38f};
  const int dbase = wv*16 + g4*4;       // my 4 consecutive d
#pragma unroll
  for (int rti = 0; rti < 8; ++rti) {
    const int rt = (rti + wv) & 7;      // stagger waves across tiles
    const int pl = rt*16 + r15;         // local row within each half (0-127)
    const int pswz = (pl & 7) << 4;
    bf16x8 pa0 = *(bf16x8*)(PA + ((pl*128 + g4*16 +  0) ^ pswz));
    bf16x8 pa1 = *(bf16x8*)(PA + ((pl*128 + g4*16 + 64) ^ pswz));
    bf16x8 pbb0 = *(bf16x8*)(PB + ((pl*128 + g4*16 +  0) ^ pswz));
    bf16x8 pbb1 = *(bf16x8*)(PB + ((pl*128 + g4*16 + 64) ^ pswz));
    f32x4 pvA = (f32x4){0.f, 0.f, 0.f, 0.f};
    f32x4 pvB = (f32x4){0.f, 0.f, 0.f, 0.f};
    pvA = __builtin_amdgcn_mfma_f32_16x16x32_bf16(au0, pa0, pvA, 0, 0, 0);
    pvA = __builtin_amdgcn_mfma_f32_16x16x32_bf16(au1, pa1, pvA, 0, 0, 0);
    pvB = __builtin_amdgcn_mfma_f32_16x16x32_bf16(au0, pbb0, pvB, 0, 0, 0);
    pvB = __builtin_amdgcn_mfma_f32_16x16x32_bf16(au1, pbb1, pvB, 0, 0, 0);
    const float prA = prow[pl],       rzA = rzrow[pl],       bmA = bm[pl];
    const float prB = prow[128 + pl], rzB = rzrow[128 + pl], bmB = bm[128 + pl];
    f32x4 h4a = *(const f32x4*)(H + (size_t)(rowB + pl)*D_ + dbase);
    f32x4 m4a = *(const f32x4*)(M + (size_t)(rowB + pl)*D_ + dbase);
    f32x4 h4b = *(const f32x4*)(H + (size_t)(rowB + 128 + pl)*D_ + dbase);
    f32x4 m4b = *(const f32x4*)(M + (size_t)(rowB + 128 + pl)*D_ + dbase);
#pragma unroll
    for (int j = 0; j < 4; ++j) {
      float cA = pvA[j] * rzA;
      float cB = pvB[j] * rzB;
      v4[j]   += prA*h4a[j] + prB*h4b[j];
      xH4[j]   = fmaxf(xH4[j],  fmaxf(h4a[j] + bmA, h4b[j] + bmB));
      nH4[j]   = fminf(nH4[j],  fminf(h4a[j] - bmA, h4b[j] - bmB));
      xC4[j]   = fmaxf(xC4[j],  fmaxf(cA + bmA, cB + bmB));
      xHC4[j]  = fmaxf(xHC4[j], fmaxf(h4a[j]*cA + bmA, h4b[j]*cB + bmB));
      xM4[j]   = fmaxf(xM4[j],  fmaxf(m4a[j] + bmA, m4b[j] + bmB));
    }
  }
  // reduce over the 16 p-lanes (r15 axis)
#pragma unroll
  for (int off = 1; off <= 8; off <<= 1) {
#pragma unroll
    for (int j = 0; j < 4; ++j) {
      v4[j]  += __shfl_xor(v4[j], off);
      xH4[j]  = fmaxf(xH4[j],  __shfl_xor(xH4[j],  off));
      nH4[j]  = fminf(nH4[j],  __shfl_xor(nH4[j],  off));
      xC4[j]  = fmaxf(xC4[j],  __shfl_xor(xC4[j],  off));
      xHC4[j] = fmaxf(xHC4[j], __shfl_xor(xHC4[j], off));
      xM4[j]  = fmaxf(xM4[j],  __shfl_xor(xM4[j],  off));
    }
  }
  float* pp = part + (size_t)bid*PART_STRIDE;
  if (t == 0) { pp[0] = Lm; pp[1] = ssum; }
  if (r15 == 0) {
#pragma unroll
    for (int j = 0; j < 4; ++j) {
      pp[2 + dbase + j]   = v4[j];
      pp[130 + dbase + j] = xH4[j];
      pp[258 + dbase + j] = nH4[j];
      pp[386 + dbase + j] = xC4[j];
      pp[514 + dbase + j] = xHC4[j];
      pp[642 + dbase + j] = xM4[j];
    }
  }
}

// ---------------------------------------------------------------------------
// k_final: merge 16 chunk-partials per batch, build pooled[640], classifier
// grid 32 (one per batch), 128 threads (t = d)
// ---------------------------------------------------------------------------
__global__ __launch_bounds__(128) void k_final(const float* __restrict__ part,
                                               const float* __restrict__ Wc,
                                               float* __restrict__ out) {
  __shared__ float pooled[640];
  __shared__ float r0s[2], r1s[2];
  const int b = blockIdx.x, t = threadIdx.x;
  const float* pb = part + (size_t)b*NCHUNK*PART_STRIDE;
  float L = -3.0e38f;
#pragma unroll
  for (int c = 0; c < NCHUNK; ++c) L = fmaxf(L, pb[c*PART_STRIDE]);
  float S = 0.f, V = 0.f;
  float mh = -3.0e38f, nh = 3.0e38f, mc = -3.0e38f, mhc = -3.0e38f, mm = -3.0e38f;
#pragma unroll
  for (int c = 0; c < NCHUNK; ++c) {
    const float* p = pb + c*PART_STRIDE;
    float e = __expf(p[0] - L);
    S += p[1]*e;
    V += p[2 + t]*e;
    mh  = fmaxf(mh,  p[130 + t]);
    nh  = fminf(nh,  p[258 + t]);
    mc  = fmaxf(mc,  p[386 + t]);
    mhc = fmaxf(mhc, p[514 + t]);
    mm  = fmaxf(mm,  p[642 + t]);
  }
  float q2c = V / S;
  pooled[t]       = mh;
  pooled[128 + t] = mc;
  pooled[256 + t] = mhc;
  pooled[384 + t] = (q2c >= 0.f) ? q2c*mh : q2c*nh;
  pooled[512 + t] = mm;
  __syncthreads();
  float a0 = 0.f, a1 = 0.f;
#pragma unroll
  for (int k = t; k < 640; k += 128) {
    float pv = pooled[k];
    a0 += pv*Wc[k*2 + 0];
    a1 += pv*Wc[k*2 + 1];
  }
#pragma unroll
  for (int off = 32; off; off >>= 1) {
    a0 += __shfl_xor(a0, off);
    a1 += __shfl_xor(a1, off);
  }
  if ((t & 63) == 0) { r0s[t >> 6] = a0; r1s[t >> 6] = a1; }
  __syncthreads();
  if (t == 0) {
    out[b*2 + 0] = r0s[0] + r0s[1];
    out[b*2 + 1] = r1s[0] + r1s[1];
  }
}

// ---------------------------------------------------------------------------
extern "C" void kernel_launch(void* const* d_in, const int* in_sizes, int n_in,
                              void* d_out, int out_size, void* d_ws, size_t ws_size,
                              hipStream_t stream) {
  const float* H   = (const float*)d_in[0];
  const float* U   = (const float*)d_in[1];
  const float* M   = (const float*)d_in[2];
  const int*   tok = (const int*)d_in[3];
  const float* Wa  = (const float*)d_in[4];
  const float* Wc  = (const float*)d_in[5];
  float* out = (float*)d_out;
  char* wsc = (char*)d_ws;
  char* Tws = wsc;
  float* part = (float*)(wsc + TWS_BYTES);

  hipLaunchKernelGGL(k_T,     dim3(256),        dim3(256), 0, stream, U, Wa, Tws);
  hipLaunchKernelGGL(k_main,  dim3(B_*NCHUNK),  dim3(512), 0, stream, H, M, tok, Tws, part);
  hipLaunchKernelGGL(k_final, dim3(B_),         dim3(128), 0, stream, part, Wc, out);
}